// Round 10
// baseline (1082.475 us; speedup 1.0000x reference)
//
#include <hip/hip_runtime.h>
#include <hip/hip_cooperative_groups.h>

namespace cg = cooperative_groups;

// ZooBP: rank-fused CSR build (R6-proven) + Jacobi iterations either as ONE
// cooperative kernel (occupancy-sized grid, launch return code CHECKED) or,
// if coop launch is rejected, the proven R6 5-dispatch loop. Both paths
// compute identical results on identical buffers.
//  - hist: atomicAdd returns = slot ranks, (ra<<8)|rp packed in ushort.
//  - adjacency entry = (idx<<13) | w13 (top 13 bits of fp32 weight; exact
//    for 1.0). Adjacency is 5-touch -> no nontemporal hints (R8 lesson).
//  - rank (4MB) aliased over ZpB (dead after scatter; ZpB first written it 0).
//  - Paper state collapses through M = SCALEF*H_ap[:4,:]@H_pa[:,:4] (4x4).

static constexpr int   DD     = 18;
static constexpr int   DIMA   = 4;
static constexpr float CCF    = 0.01f;
static constexpr float SCALEF = 0.1f / 18.0f;
static constexpr int   PROP   = 5;

__device__ __forceinline__ float bf2f(unsigned short u) {
    return __uint_as_float(((unsigned int)u) << 16);
}
__device__ __forceinline__ unsigned short f2bf(float f) {
    unsigned int x = __float_as_uint(f);
    return (unsigned short)((x + 0x7fffu + ((x >> 16) & 1u)) >> 16);
}
__device__ __forceinline__ unsigned int f2w13(float f) {
    unsigned int x = __float_as_uint(f);
    return ((x + 0x3ffffu + ((x >> 19) & 1u)) >> 19) & 0x1fffu;
}
__device__ __forceinline__ float w132f(unsigned int u) {
    return __uint_as_float(u << 19);
}

__global__ __launch_bounds__(256) void hist(
    const int* __restrict__ esrc, const int* __restrict__ edst,
    int* __restrict__ cnt, unsigned short* __restrict__ rank, int NP, int E)
{
    int base = (blockIdx.x * 256 + threadIdx.x) * 2;
    if (base >= E) return;
    if (base + 1 < E) {
        int2 s2 = *(const int2*)(esrc + base);
        int2 d2 = *(const int2*)(edst + base);
        unsigned int rp0 = (unsigned int)atomicAdd(&cnt[d2.x], 1);
        unsigned int ra0 = (unsigned int)atomicAdd(&cnt[NP + s2.x], 1);
        unsigned int rp1 = (unsigned int)atomicAdd(&cnt[d2.y], 1);
        unsigned int ra1 = (unsigned int)atomicAdd(&cnt[NP + s2.y], 1);
        unsigned int r0 = (ra0 << 8) | rp0;
        unsigned int r1 = (ra1 << 8) | rp1;
        *(unsigned int*)(rank + base) = r0 | (r1 << 16);
    } else {
        unsigned int rp = (unsigned int)atomicAdd(&cnt[edst[base]], 1);
        unsigned int ra = (unsigned int)atomicAdd(&cnt[NP + esrc[base]], 1);
        rank[base] = (unsigned short)((ra << 8) | rp);
    }
}

__global__ __launch_bounds__(256) void scan_block(
    int* __restrict__ off, int* __restrict__ bsum, int NT)
{
    __shared__ int s[256];
    int t = threadIdx.x;
    int i = blockIdx.x * 256 + t;
    int v = (i < NT) ? off[i] : 0;
    s[t] = v; __syncthreads();
    for (int dlt = 1; dlt < 256; dlt <<= 1) {
        int x = (t >= dlt) ? s[t - dlt] : 0;
        __syncthreads();
        s[t] += x;
        __syncthreads();
    }
    if (i < NT) off[i] = s[t] - v;
    if (t == 255) bsum[blockIdx.x] = s[255];
}

__global__ __launch_bounds__(256) void scan_tops(int* __restrict__ bsum, int nb)
{
    __shared__ int s[256];
    int t = threadIdx.x;
    int K = (nb + 255) / 256;
    int base = t * K;
    int sum = 0;
    for (int r = 0; r < K; ++r) { int idx = base + r; if (idx < nb) sum += bsum[idx]; }
    s[t] = sum; __syncthreads();
    for (int dlt = 1; dlt < 256; dlt <<= 1) {
        int x = (t >= dlt) ? s[t - dlt] : 0;
        __syncthreads();
        s[t] += x;
        __syncthreads();
    }
    int run = s[t] - sum;
    for (int r = 0; r < K; ++r) {
        int idx = base + r;
        if (idx < nb) { int tmp = bsum[idx]; bsum[idx] = run; run += tmp; }
    }
}

__global__ __launch_bounds__(256) void scan_add(
    int* __restrict__ off, const int* __restrict__ bsum, int NT, int twoE)
{
    int i = blockIdx.x * 256 + threadIdx.x;
    if (i < NT)       off[i] += bsum[i >> 8];
    else if (i == NT) off[NT] = twoE;
}

__global__ __launch_bounds__(256) void scatter_init(
    const int* __restrict__ esrc, const int* __restrict__ edst,
    const float* __restrict__ w, const unsigned short* __restrict__ rank,
    const int* __restrict__ off,
    unsigned int* __restrict__ adjP, unsigned int* __restrict__ adjA,
    const int* __restrict__ mask_a, const int* __restrict__ lab_a,
    const int* __restrict__ mask_p, const int* __restrict__ lab_p,
    const float* __restrict__ Hpa,
    ushort4* __restrict__ Ya, ushort4* __restrict__ Zp,
    int NP, int NA, int E, int NT, int geB)
{
    if ((int)blockIdx.x < geB) {
        int e = blockIdx.x * 256 + threadIdx.x;
        if (e >= E) return;
        int s = esrc[e], d = edst[e];
        unsigned int r  = rank[e];
        unsigned int wb = f2w13(w[e]);
        int sp = off[d] + (int)(r & 0xffu);
        adjP[sp] = ((unsigned int)s << 13) | wb;
        int sa = off[NP + s] + (int)(r >> 8) - E;
        adjA[sa] = ((unsigned int)d << 13) | wb;
    } else {
        __shared__ float sH[72], sCol[4];
        int t = threadIdx.x;
        if (t < 72) sH[t] = Hpa[(t >> 2) * DD + (t & 3)];
        if (t < 4) { float s = 0.f; for (int k = 0; k < DD; ++k) s += Hpa[k * DD + t]; sCol[t] = s; }
        __syncthreads();
        int i = ((int)blockIdx.x - geB) * 256 + t;
        if (i >= NT) return;
        if (i < NA) {
            float x[4] = {0.f, 0.f, 0.f, 0.f};
            if (mask_a[i]) {
                x[0] = x[1] = x[2] = x[3] = -CCF;
                x[lab_a[i]] += (float)DIMA * CCF;
            }
            Ya[i] = make_ushort4(f2bf(x[0]), f2bf(x[1]), f2bf(x[2]), f2bf(x[3]));
        } else {
            int d = i - NA;
            float z0 = 0.f, z1 = 0.f, z2 = 0.f, z3 = 0.f;
            if (mask_p[d]) {
                int l = lab_p[d];
                float lb = (float)DD * CCF;
                z0 = -CCF * sCol[0] + lb * sH[l * 4 + 0];
                z1 = -CCF * sCol[1] + lb * sH[l * 4 + 1];
                z2 = -CCF * sCol[2] + lb * sH[l * 4 + 2];
                z3 = -CCF * sCol[3] + lb * sH[l * 4 + 3];
            }
            Zp[d] = make_ushort4(f2bf(z0), f2bf(z1), f2bf(z2), f2bf(z3));
        }
    }
}

// ---- shared per-iteration device code (used by both paths) ----
__device__ __forceinline__ void paper_node(
    int d, const int* __restrict__ off, const unsigned int* __restrict__ adjP,
    const ushort4* __restrict__ YaOld, ushort4* __restrict__ ZpNew,
    const int* __restrict__ mask_p, const int* __restrict__ lab_p,
    const float* sH, const float* sCol, const float* sM, const float* sHap,
    float* __restrict__ out, int NA, int last)
{
    int beg = off[d], end = off[d + 1];
    float ax = 0.f, ay = 0.f, az = 0.f, aw = 0.f;
    for (int s = beg; s < end; ++s) {
        unsigned int ent = adjP[s];
        float wt = w132f(ent & 0x1fffu);
        ushort4 yv = YaOld[ent >> 13];
        ax += wt * bf2f(yv.x); ay += wt * bf2f(yv.y);
        az += wt * bf2f(yv.z); aw += wt * bf2f(yv.w);
    }
    int m = mask_p[d];
    int l = m ? lab_p[d] : 0;
    float base = m ? -CCF : 0.f;
    float lb   = m ? (float)DD * CCF : 0.f;
    float z0 = base * sCol[0] + lb * sH[l * 4 + 0] + ax * sM[0] + ay * sM[4] + az * sM[8]  + aw * sM[12];
    float z1 = base * sCol[1] + lb * sH[l * 4 + 1] + ax * sM[1] + ay * sM[5] + az * sM[9]  + aw * sM[13];
    float z2 = base * sCol[2] + lb * sH[l * 4 + 2] + ax * sM[2] + ay * sM[6] + az * sM[10] + aw * sM[14];
    float z3 = base * sCol[3] + lb * sH[l * 4 + 3] + ax * sM[3] + ay * sM[7] + az * sM[11] + aw * sM[15];
    ZpNew[d] = make_ushort4(f2bf(z0), f2bf(z1), f2bf(z2), f2bf(z3));
    if (last) {
        float* row = out + (size_t)(NA + d) * DD;
#pragma unroll
        for (int j = 0; j < DD; ++j) {
            row[j] = base + ((j == l) ? lb : 0.f)
                   + ax * sHap[0 * DD + j] + ay * sHap[1 * DD + j]
                   + az * sHap[2 * DD + j] + aw * sHap[3 * DD + j];
        }
    }
}

__device__ __forceinline__ void author_node(
    int a, int sub, const int* __restrict__ off,
    const unsigned int* __restrict__ adjA, const ushort4* __restrict__ ZpOld,
    const int* __restrict__ mask_a, const int* __restrict__ lab_a,
    ushort4* __restrict__ YaNew, float* __restrict__ out,
    int NP, int E, int last)
{
    int beg = off[NP + a] - E, end = off[NP + a + 1] - E;
    float ax = 0.f, ay = 0.f, az = 0.f, aw = 0.f;
    for (int s = beg + sub; s < end; s += 4) {
        unsigned int ent = adjA[s];
        float wt = w132f(ent & 0x1fffu);
        ushort4 z = ZpOld[ent >> 13];
        ax += wt * bf2f(z.x); ay += wt * bf2f(z.y);
        az += wt * bf2f(z.z); aw += wt * bf2f(z.w);
    }
    ax += __shfl_xor(ax, 1); ay += __shfl_xor(ay, 1);
    az += __shfl_xor(az, 1); aw += __shfl_xor(aw, 1);
    ax += __shfl_xor(ax, 2); ay += __shfl_xor(ay, 2);
    az += __shfl_xor(az, 2); aw += __shfl_xor(aw, 2);
    if (sub == 0) {
        float x[4] = {0.f, 0.f, 0.f, 0.f};
        if (mask_a[a]) {
            x[0] = x[1] = x[2] = x[3] = -CCF;
            x[lab_a[a]] += (float)DIMA * CCF;
        }
        float y0 = x[0] + SCALEF * ax, y1 = x[1] + SCALEF * ay;
        float y2 = x[2] + SCALEF * az, y3 = x[3] + SCALEF * aw;
        YaNew[a] = make_ushort4(f2bf(y0), f2bf(y1), f2bf(y2), f2bf(y3));
        if (last) {
            float* row = out + (size_t)a * DD;
            row[0] = y0; row[1] = y1; row[2] = y2; row[3] = y3;
#pragma unroll
            for (int j = DIMA; j < DD; ++j) row[j] = 0.f;
        }
    }
}

#define LOAD_CONSTS()                                                          \
    __shared__ float sH[72], sCol[4], sM[16], sHap[72];                        \
    {                                                                          \
        int t = threadIdx.x;                                                   \
        if (t < 72) sH[t] = Hpa[(t >> 2) * DD + (t & 3)];                      \
        if (t < 4) { float s_ = 0.f; for (int k = 0; k < DD; ++k) s_ += Hpa[k * DD + t]; sCol[t] = s_; } \
        if (t < 16) { int i_ = t >> 2, j_ = t & 3; float s_ = 0.f;             \
                      for (int k = 0; k < DD; ++k) s_ += Hap[i_ * DD + k] * Hpa[k * DD + j_]; \
                      sM[t] = SCALEF * s_; }                                   \
        if (t < 72) sHap[t] = SCALEF * Hap[t];                                 \
    }                                                                          \
    __syncthreads();

// Fallback: one dispatch per iteration (R6 structure, proven 528 us).
__global__ __launch_bounds__(256) void gather_iter(
    const int* __restrict__ off,
    const unsigned int* __restrict__ adjP, const unsigned int* __restrict__ adjA,
    const ushort4* __restrict__ ZpOld, ushort4* __restrict__ ZpNew,
    const ushort4* __restrict__ YaOld, ushort4* __restrict__ YaNew,
    const int* __restrict__ mask_a, const int* __restrict__ lab_a,
    const int* __restrict__ mask_p, const int* __restrict__ lab_p,
    const float* __restrict__ Hap, const float* __restrict__ Hpa,
    float* __restrict__ out, int NP, int NA, int E, int last, int gpB)
{
    if ((int)blockIdx.x < gpB) {
        LOAD_CONSTS();
        int d = (int)blockIdx.x * 256 + threadIdx.x;
        if (d >= NP) return;
        paper_node(d, off, adjP, YaOld, ZpNew, mask_p, lab_p,
                   sH, sCol, sM, sHap, out, NA, last);
    } else {
        int tid = ((int)blockIdx.x - gpB) * 256 + threadIdx.x;
        int a = tid >> 2, sub = tid & 3;
        if (a >= NA) return;
        author_node(a, sub, off, adjA, ZpOld, mask_a, lab_a, YaNew, out,
                    NP, E, last);
    }
}

// Cooperative: all 5 iterations, grid.sync between them.
__global__ __launch_bounds__(256) void gather_all(
    const int* __restrict__ off,
    const unsigned int* __restrict__ adjP, const unsigned int* __restrict__ adjA,
    ushort4* __restrict__ ZpA, ushort4* __restrict__ ZpB,
    ushort4* __restrict__ YaA, ushort4* __restrict__ YaB,
    const int* __restrict__ mask_a, const int* __restrict__ lab_a,
    const int* __restrict__ mask_p, const int* __restrict__ lab_p,
    const float* __restrict__ Hap, const float* __restrict__ Hpa,
    float* __restrict__ out, int NP, int NA, int E)
{
    cg::grid_group grid = cg::this_grid();
    LOAD_CONSTS();

    const int gsz = (int)gridDim.x * 256;
    const int gid = (int)blockIdx.x * 256 + (int)threadIdx.x;
    const int na4 = NA * 4;

    for (int it = 0; it < PROP; ++it) {
        const int last = (it == PROP - 1);
        const ushort4* ZpOld = (it & 1) ? ZpB : ZpA;
        ushort4*       ZpNew = (it & 1) ? ZpA : ZpB;
        const ushort4* YaOld = (it & 1) ? YaB : YaA;
        ushort4*       YaNew = (it & 1) ? YaA : YaB;

        for (int d = gid; d < NP; d += gsz)
            paper_node(d, off, adjP, YaOld, ZpNew, mask_p, lab_p,
                       sH, sCol, sM, sHap, out, NA, last);

        for (int u = gid; u < na4; u += gsz)
            author_node(u >> 2, u & 3, off, adjA, ZpOld, mask_a, lab_a,
                        YaNew, out, NP, E, last);

        if (it != PROP - 1) {
            __threadfence();
            grid.sync();
        }
    }
}

extern "C" void kernel_launch(void* const* d_in, const int* in_sizes, int n_in,
                              void* d_out, int out_size, void* d_ws, size_t ws_size,
                              hipStream_t stream)
{
    const float* H_ap   = (const float*)d_in[0];
    const float* H_pa   = (const float*)d_in[1];
    const float* w      = (const float*)d_in[2];
    const int*   esrc   = (const int*)d_in[3];
    const int*   edst   = (const int*)d_in[4];
    const int*   mask_a = (const int*)d_in[5];
    const int*   lab_a  = (const int*)d_in[6];
    const int*   mask_p = (const int*)d_in[7];
    const int*   lab_p  = (const int*)d_in[8];

    const int E  = in_sizes[2];
    const int NA = in_sizes[5];
    const int NP = in_sizes[7];
    const int NT = NP + NA;
    const int nb = (NT + 255) / 256;

    // workspace (~28 MB)
    char*  basep = (char*)d_ws;
    size_t o = 0;
    auto alloc = [&](size_t bytes) -> char* {
        o = (o + 15) & ~(size_t)15;
        char* p = basep + o;
        o += bytes;
        return p;
    };
    int*          off  = (int*)         alloc((size_t)(NT + 1) * sizeof(int));
    int*          bsum = (int*)         alloc((size_t)4096 * sizeof(int));
    unsigned int* adjP = (unsigned int*)alloc((size_t)E * sizeof(unsigned int));
    unsigned int* adjA = (unsigned int*)alloc((size_t)E * sizeof(unsigned int));
    ushort4*      YaA  = (ushort4*)     alloc((size_t)NA * sizeof(ushort4));
    ushort4*      YaB  = (ushort4*)     alloc((size_t)NA * sizeof(ushort4));
    ushort4*      ZpA  = (ushort4*)     alloc((size_t)NP * sizeof(ushort4));
    size_t zp_bytes = (size_t)NP * sizeof(ushort4);
    size_t rk_bytes = (size_t)E * sizeof(unsigned short);
    ushort4*      ZpB  = (ushort4*)     alloc(zp_bytes > rk_bytes ? zp_bytes : rk_bytes);
    unsigned short* rank = (unsigned short*)ZpB;  // alias: rank dead before ZpB written
    (void)ws_size;

    float* out = (float*)d_out;

    dim3 blk(256);
    int gp   = (NP + 255) / 256;
    int ge   = (E + 255) / 256;
    int gh   = ((E + 1) / 2 + 255) / 256;
    int ga4  = (NA * 4 + 255) / 256;
    int gni  = (NT + 255) / 256;
    int gnt1 = (NT + 1 + 255) / 256;

    hipMemsetAsync(off, 0, (size_t)(NT + 1) * sizeof(int), stream);
    hist<<<gh, blk, 0, stream>>>(esrc, edst, off, rank, NP, E);
    scan_block<<<nb, blk, 0, stream>>>(off, bsum, NT);
    scan_tops<<<1, blk, 0, stream>>>(bsum, nb);
    scan_add<<<gnt1, blk, 0, stream>>>(off, bsum, NT, 2 * E);
    scatter_init<<<ge + gni, blk, 0, stream>>>(esrc, edst, w, rank, off,
                                               adjP, adjA, mask_a, lab_a,
                                               mask_p, lab_p, H_pa,
                                               YaA, ZpA, NP, NA, E, NT, ge);

    // Try the cooperative single-dispatch path; fall back to 5 dispatches.
    bool coop_done = false;
    {
        int occ = 0;
        hipError_t qe = hipOccupancyMaxActiveBlocksPerMultiprocessor(
            &occ, (const void*)gather_all, 256, 0);
        if (qe == hipSuccess && occ > 0) {
            int maxg = occ * 256;              // 256 CUs on MI355X
            int g = maxg < 2048 ? maxg : 2048; // cap: plenty of parallelism
            void* args[] = {
                (void*)&off, (void*)&adjP, (void*)&adjA,
                (void*)&ZpA, (void*)&ZpB, (void*)&YaA, (void*)&YaB,
                (void*)&mask_a, (void*)&lab_a, (void*)&mask_p, (void*)&lab_p,
                (void*)&H_ap, (void*)&H_pa, (void*)&out,
                (void*)&NP, (void*)&NA, (void*)&E
            };
            hipError_t le = hipLaunchCooperativeKernel(
                (const void*)gather_all, dim3(g), blk, args, 0, stream);
            coop_done = (le == hipSuccess);
        }
    }
    if (!coop_done) {
        ushort4* YaBuf[2] = {YaA, YaB};
        ushort4* ZpBuf[2] = {ZpA, ZpB};
        for (int it = 0; it < PROP; ++it) {
            int last = (it == PROP - 1) ? 1 : 0;
            int cur = it & 1, nxt = 1 - cur;
            gather_iter<<<gp + ga4, blk, 0, stream>>>(off, adjP, adjA,
                                                      ZpBuf[cur], ZpBuf[nxt],
                                                      YaBuf[cur], YaBuf[nxt],
                                                      mask_a, lab_a, mask_p, lab_p,
                                                      H_ap, H_pa, out,
                                                      NP, NA, E, last, gp);
        }
    }
}

// Round 11
// 537.876 us; speedup vs baseline: 2.0125x; 2.0125x over previous
//
#include <hip/hip_runtime.h>

// ZooBP: rank-fused CSR build + bf16 double-buffered gathers (R6-proven
// structure). R11: deeper per-node thread teams in the gathers to cut the
// serialized latency chain (papers 2 thr/node, authors 8 thr/node).
//  - hist: atomicAdd returns = slot ranks, (ra<<8)|rp packed in ushort.
//  - adjacency entry = (idx<<13) | w13 (top 13 bits of fp32 w; exact for 1.0).
//    Adjacency is 5-touch -> no nontemporal hints (R8 lesson).
//  - rank (4MB) aliased over ZpB (dead after scatter; ZpB first written it 0).
//  - Paper state collapses through M = SCALEF*H_ap[:4,:]@H_pa[:,:4] (4x4).
//  - NO cooperative launch: grid.sync on multi-XCD flushes per-XCD L2s and
//    regressed 2x (R10); separate dispatches keep L2 warm.

static constexpr int   DD     = 18;
static constexpr int   DIMA   = 4;
static constexpr float CCF    = 0.01f;
static constexpr float SCALEF = 0.1f / 18.0f;
static constexpr int   PROP   = 5;

__device__ __forceinline__ float bf2f(unsigned short u) {
    return __uint_as_float(((unsigned int)u) << 16);
}
__device__ __forceinline__ unsigned short f2bf(float f) {
    unsigned int x = __float_as_uint(f);
    return (unsigned short)((x + 0x7fffu + ((x >> 16) & 1u)) >> 16);
}
__device__ __forceinline__ unsigned int f2w13(float f) {
    unsigned int x = __float_as_uint(f);
    return ((x + 0x3ffffu + ((x >> 19) & 1u)) >> 19) & 0x1fffu;
}
__device__ __forceinline__ float w132f(unsigned int u) {
    return __uint_as_float(u << 19);
}

// Histogram; atomic return values are the per-edge slot ranks (8+8 bit packed).
__global__ __launch_bounds__(256) void hist(
    const int* __restrict__ esrc, const int* __restrict__ edst,
    int* __restrict__ cnt, unsigned short* __restrict__ rank, int NP, int E)
{
    int base = (blockIdx.x * 256 + threadIdx.x) * 2;
    if (base >= E) return;
    if (base + 1 < E) {
        int2 s2 = *(const int2*)(esrc + base);
        int2 d2 = *(const int2*)(edst + base);
        unsigned int rp0 = (unsigned int)atomicAdd(&cnt[d2.x], 1);
        unsigned int ra0 = (unsigned int)atomicAdd(&cnt[NP + s2.x], 1);
        unsigned int rp1 = (unsigned int)atomicAdd(&cnt[d2.y], 1);
        unsigned int ra1 = (unsigned int)atomicAdd(&cnt[NP + s2.y], 1);
        unsigned int r0 = (ra0 << 8) | rp0;
        unsigned int r1 = (ra1 << 8) | rp1;
        *(unsigned int*)(rank + base) = r0 | (r1 << 16);
    } else {
        unsigned int rp = (unsigned int)atomicAdd(&cnt[edst[base]], 1);
        unsigned int ra = (unsigned int)atomicAdd(&cnt[NP + esrc[base]], 1);
        rank[base] = (unsigned short)((ra << 8) | rp);
    }
}

__global__ __launch_bounds__(256) void scan_block(
    int* __restrict__ off, int* __restrict__ bsum, int NT)
{
    __shared__ int s[256];
    int t = threadIdx.x;
    int i = blockIdx.x * 256 + t;
    int v = (i < NT) ? off[i] : 0;
    s[t] = v; __syncthreads();
    for (int dlt = 1; dlt < 256; dlt <<= 1) {
        int x = (t >= dlt) ? s[t - dlt] : 0;
        __syncthreads();
        s[t] += x;
        __syncthreads();
    }
    if (i < NT) off[i] = s[t] - v;
    if (t == 255) bsum[blockIdx.x] = s[255];
}

__global__ __launch_bounds__(256) void scan_tops(int* __restrict__ bsum, int nb)
{
    __shared__ int s[256];
    int t = threadIdx.x;
    int K = (nb + 255) / 256;
    int base = t * K;
    int sum = 0;
    for (int r = 0; r < K; ++r) { int idx = base + r; if (idx < nb) sum += bsum[idx]; }
    s[t] = sum; __syncthreads();
    for (int dlt = 1; dlt < 256; dlt <<= 1) {
        int x = (t >= dlt) ? s[t - dlt] : 0;
        __syncthreads();
        s[t] += x;
        __syncthreads();
    }
    int run = s[t] - sum;
    for (int r = 0; r < K; ++r) {
        int idx = base + r;
        if (idx < nb) { int tmp = bsum[idx]; bsum[idx] = run; run += tmp; }
    }
}

__global__ __launch_bounds__(256) void scan_add(
    int* __restrict__ off, const int* __restrict__ bsum, int NT, int twoE)
{
    int i = blockIdx.x * 256 + threadIdx.x;
    if (i < NT)       off[i] += bsum[i >> 8];
    else if (i == NT) off[NT] = twoE;
}

// Fused: blocks [0,geB) atomic-free scatter (4B packed stores);
//        blocks [geB,..) belief init (Ya0 bf16x4, Zp0 = Yp0 @ H_pa[:,:4]).
__global__ __launch_bounds__(256) void scatter_init(
    const int* __restrict__ esrc, const int* __restrict__ edst,
    const float* __restrict__ w, const unsigned short* __restrict__ rank,
    const int* __restrict__ off,
    unsigned int* __restrict__ adjP, unsigned int* __restrict__ adjA,
    const int* __restrict__ mask_a, const int* __restrict__ lab_a,
    const int* __restrict__ mask_p, const int* __restrict__ lab_p,
    const float* __restrict__ Hpa,
    ushort4* __restrict__ Ya, ushort4* __restrict__ Zp,
    int NP, int NA, int E, int NT, int geB)
{
    if ((int)blockIdx.x < geB) {
        int e = blockIdx.x * 256 + threadIdx.x;
        if (e >= E) return;
        int s = esrc[e], d = edst[e];
        unsigned int r  = rank[e];
        unsigned int wb = f2w13(w[e]);
        int sp = off[d] + (int)(r & 0xffu);
        adjP[sp] = ((unsigned int)s << 13) | wb;
        int sa = off[NP + s] + (int)(r >> 8) - E;
        adjA[sa] = ((unsigned int)d << 13) | wb;
    } else {
        __shared__ float sH[72], sCol[4];
        int t = threadIdx.x;
        if (t < 72) sH[t] = Hpa[(t >> 2) * DD + (t & 3)];
        if (t < 4) { float s = 0.f; for (int k = 0; k < DD; ++k) s += Hpa[k * DD + t]; sCol[t] = s; }
        __syncthreads();
        int i = ((int)blockIdx.x - geB) * 256 + t;
        if (i >= NT) return;
        if (i < NA) {
            float x[4] = {0.f, 0.f, 0.f, 0.f};
            if (mask_a[i]) {
                x[0] = x[1] = x[2] = x[3] = -CCF;
                x[lab_a[i]] += (float)DIMA * CCF;
            }
            Ya[i] = make_ushort4(f2bf(x[0]), f2bf(x[1]), f2bf(x[2]), f2bf(x[3]));
        } else {
            int d = i - NA;
            float z0 = 0.f, z1 = 0.f, z2 = 0.f, z3 = 0.f;
            if (mask_p[d]) {
                int l = lab_p[d];
                float lb = (float)DD * CCF;
                z0 = -CCF * sCol[0] + lb * sH[l * 4 + 0];
                z1 = -CCF * sCol[1] + lb * sH[l * 4 + 1];
                z2 = -CCF * sCol[2] + lb * sH[l * 4 + 2];
                z3 = -CCF * sCol[3] + lb * sH[l * 4 + 3];
            }
            Zp[d] = make_ushort4(f2bf(z0), f2bf(z1), f2bf(z2), f2bf(z3));
        }
    }
}

// One fused Jacobi step. Papers: 2 threads/node; Authors: 8 threads/node.
// Papers read YaOld -> ZpNew; Authors read ZpOld -> YaNew (double-buffered,
// so the two phases are independent). last -> write fp32 out rows.
__global__ __launch_bounds__(256) void gather_iter(
    const int* __restrict__ off,
    const unsigned int* __restrict__ adjP, const unsigned int* __restrict__ adjA,
    const ushort4* __restrict__ ZpOld, ushort4* __restrict__ ZpNew,
    const ushort4* __restrict__ YaOld, ushort4* __restrict__ YaNew,
    const int* __restrict__ mask_a, const int* __restrict__ lab_a,
    const int* __restrict__ mask_p, const int* __restrict__ lab_p,
    const float* __restrict__ Hap, const float* __restrict__ Hpa,
    float* __restrict__ out, int NP, int NA, int E, int last, int gpB)
{
    if ((int)blockIdx.x < gpB) {
        // ---- papers: 2 threads per node ----
        __shared__ float sH[72], sCol[4], sM[16], sHap[72];
        int t = threadIdx.x;
        if (t < 72) sH[t] = Hpa[(t >> 2) * DD + (t & 3)];
        if (t < 4) { float s = 0.f; for (int k = 0; k < DD; ++k) s += Hpa[k * DD + t]; sCol[t] = s; }
        if (t < 16) { int i = t >> 2, j = t & 3; float s = 0.f;
                      for (int k = 0; k < DD; ++k) s += Hap[i * DD + k] * Hpa[k * DD + j];
                      sM[t] = SCALEF * s; }
        if (t < 72) sHap[t] = SCALEF * Hap[t];
        __syncthreads();

        int tid = (int)blockIdx.x * 256 + t;
        int d = tid >> 1, sub = tid & 1;
        if (d >= NP) return;
        int beg = off[d], end = off[d + 1];
        float ax = 0.f, ay = 0.f, az = 0.f, aw = 0.f;
        for (int s = beg + sub; s < end; s += 2) {
            unsigned int ent = adjP[s];
            float wt = w132f(ent & 0x1fffu);
            ushort4 yv = YaOld[ent >> 13];
            ax += wt * bf2f(yv.x); ay += wt * bf2f(yv.y);
            az += wt * bf2f(yv.z); aw += wt * bf2f(yv.w);
        }
        ax += __shfl_xor(ax, 1); ay += __shfl_xor(ay, 1);
        az += __shfl_xor(az, 1); aw += __shfl_xor(aw, 1);
        if (sub) return;

        int m = mask_p[d];
        int l = m ? lab_p[d] : 0;
        float base = m ? -CCF : 0.f;
        float lb   = m ? (float)DD * CCF : 0.f;
        float z0 = base * sCol[0] + lb * sH[l * 4 + 0] + ax * sM[0] + ay * sM[4] + az * sM[8]  + aw * sM[12];
        float z1 = base * sCol[1] + lb * sH[l * 4 + 1] + ax * sM[1] + ay * sM[5] + az * sM[9]  + aw * sM[13];
        float z2 = base * sCol[2] + lb * sH[l * 4 + 2] + ax * sM[2] + ay * sM[6] + az * sM[10] + aw * sM[14];
        float z3 = base * sCol[3] + lb * sH[l * 4 + 3] + ax * sM[3] + ay * sM[7] + az * sM[11] + aw * sM[15];
        ZpNew[d] = make_ushort4(f2bf(z0), f2bf(z1), f2bf(z2), f2bf(z3));

        if (last) {
            float* row = out + (size_t)(NA + d) * DD;
#pragma unroll
            for (int j = 0; j < DD; ++j) {
                row[j] = base + ((j == l) ? lb : 0.f)
                       + ax * sHap[0 * DD + j] + ay * sHap[1 * DD + j]
                       + az * sHap[2 * DD + j] + aw * sHap[3 * DD + j];
            }
        }
    } else {
        // ---- authors: 8 threads per node ----
        int tid = ((int)blockIdx.x - gpB) * 256 + threadIdx.x;
        int a = tid >> 3, sub = tid & 7;
        if (a >= NA) return;
        int beg = off[NP + a] - E, end = off[NP + a + 1] - E;
        float ax = 0.f, ay = 0.f, az = 0.f, aw = 0.f;
        for (int s = beg + sub; s < end; s += 8) {
            unsigned int ent = adjA[s];
            float wt = w132f(ent & 0x1fffu);
            ushort4 z = ZpOld[ent >> 13];
            ax += wt * bf2f(z.x); ay += wt * bf2f(z.y);
            az += wt * bf2f(z.z); aw += wt * bf2f(z.w);
        }
        ax += __shfl_xor(ax, 1); ay += __shfl_xor(ay, 1);
        az += __shfl_xor(az, 1); aw += __shfl_xor(aw, 1);
        ax += __shfl_xor(ax, 2); ay += __shfl_xor(ay, 2);
        az += __shfl_xor(az, 2); aw += __shfl_xor(aw, 2);
        ax += __shfl_xor(ax, 4); ay += __shfl_xor(ay, 4);
        az += __shfl_xor(az, 4); aw += __shfl_xor(aw, 4);
        if (sub == 0) {
            float x[4] = {0.f, 0.f, 0.f, 0.f};
            if (mask_a[a]) {
                x[0] = x[1] = x[2] = x[3] = -CCF;
                x[lab_a[a]] += (float)DIMA * CCF;
            }
            float y0 = x[0] + SCALEF * ax, y1 = x[1] + SCALEF * ay;
            float y2 = x[2] + SCALEF * az, y3 = x[3] + SCALEF * aw;
            YaNew[a] = make_ushort4(f2bf(y0), f2bf(y1), f2bf(y2), f2bf(y3));
            if (last) {
                float* row = out + (size_t)a * DD;
                row[0] = y0; row[1] = y1; row[2] = y2; row[3] = y3;
#pragma unroll
                for (int j = DIMA; j < DD; ++j) row[j] = 0.f;
            }
        }
    }
}

extern "C" void kernel_launch(void* const* d_in, const int* in_sizes, int n_in,
                              void* d_out, int out_size, void* d_ws, size_t ws_size,
                              hipStream_t stream)
{
    const float* H_ap   = (const float*)d_in[0];
    const float* H_pa   = (const float*)d_in[1];
    const float* w      = (const float*)d_in[2];
    const int*   esrc   = (const int*)d_in[3];
    const int*   edst   = (const int*)d_in[4];
    const int*   mask_a = (const int*)d_in[5];
    const int*   lab_a  = (const int*)d_in[6];
    const int*   mask_p = (const int*)d_in[7];
    const int*   lab_p  = (const int*)d_in[8];

    const int E  = in_sizes[2];
    const int NA = in_sizes[5];
    const int NP = in_sizes[7];
    const int NT = NP + NA;
    const int nb = (NT + 255) / 256;

    // workspace (~28 MB)
    char*  basep = (char*)d_ws;
    size_t o = 0;
    auto alloc = [&](size_t bytes) -> char* {
        o = (o + 15) & ~(size_t)15;
        char* p = basep + o;
        o += bytes;
        return p;
    };
    int*          off  = (int*)         alloc((size_t)(NT + 1) * sizeof(int));
    int*          bsum = (int*)         alloc((size_t)4096 * sizeof(int));
    unsigned int* adjP = (unsigned int*)alloc((size_t)E * sizeof(unsigned int));
    unsigned int* adjA = (unsigned int*)alloc((size_t)E * sizeof(unsigned int));
    ushort4*      YaA  = (ushort4*)     alloc((size_t)NA * sizeof(ushort4));
    ushort4*      YaB  = (ushort4*)     alloc((size_t)NA * sizeof(ushort4));
    ushort4*      ZpA  = (ushort4*)     alloc((size_t)NP * sizeof(ushort4));
    size_t zp_bytes = (size_t)NP * sizeof(ushort4);
    size_t rk_bytes = (size_t)E * sizeof(unsigned short);
    ushort4*      ZpB  = (ushort4*)     alloc(zp_bytes > rk_bytes ? zp_bytes : rk_bytes);
    unsigned short* rank = (unsigned short*)ZpB;  // alias: rank dead before ZpB written
    (void)ws_size;

    float* out = (float*)d_out;
    ushort4* YaBuf[2] = {YaA, YaB};
    ushort4* ZpBuf[2] = {ZpA, ZpB};

    dim3 blk(256);
    int gp2  = (NP * 2 + 255) / 256;   // papers, 2 threads each
    int ge   = (E + 255) / 256;
    int gh   = ((E + 1) / 2 + 255) / 256;
    int ga8  = (NA * 8 + 255) / 256;   // authors, 8 threads each
    int gni  = (NT + 255) / 256;
    int gnt1 = (NT + 1 + 255) / 256;

    hipMemsetAsync(off, 0, (size_t)(NT + 1) * sizeof(int), stream);
    hist<<<gh, blk, 0, stream>>>(esrc, edst, off, rank, NP, E);
    scan_block<<<nb, blk, 0, stream>>>(off, bsum, NT);
    scan_tops<<<1, blk, 0, stream>>>(bsum, nb);
    scan_add<<<gnt1, blk, 0, stream>>>(off, bsum, NT, 2 * E);
    scatter_init<<<ge + gni, blk, 0, stream>>>(esrc, edst, w, rank, off,
                                               adjP, adjA, mask_a, lab_a,
                                               mask_p, lab_p, H_pa,
                                               YaA, ZpA, NP, NA, E, NT, ge);

    for (int it = 0; it < PROP; ++it) {
        int last = (it == PROP - 1) ? 1 : 0;
        int cur = it & 1, nxt = 1 - cur;
        gather_iter<<<gp2 + ga8, blk, 0, stream>>>(off, adjP, adjA,
                                                   ZpBuf[cur], ZpBuf[nxt],
                                                   YaBuf[cur], YaBuf[nxt],
                                                   mask_a, lab_a, mask_p, lab_p,
                                                   H_ap, H_pa, out,
                                                   NP, NA, E, last, gp2);
    }
}